// Round 8
// baseline (416.120 us; speedup 1.0000x reference)
//
#include <hip/hip_runtime.h>

// PointNetKnnInterpolator on MI355X (gfx950).
// R18: clean 6-waves/SIMD occupancy test (3 blocks/CU).
// Clock discovery (R12/R16/R17 cross-check): MfmaUtil*wall == MFMA pipe-cycles
// only at ~800MHz effective clock -> per-pair budget (R12): VALU 990cy (34%)
// + MFMA 480 (16%) + LDS 600 (20%) + stall 800 (29%) => ~70% issue-bound;
// more waves is the remaining lever. Requirements for 3 blocks/CU:
// LDS <= 53.3KB (ok: 49.7KB, no ebuf) and <=85 regs/wave. This body is lean
// by construction: 1 tile/iter, ONLY 2 acc arrays ever live (mm4 reuses A1's
// slots - R14-verified), reg-only shfl_xor epilogue (R16-verified numerics),
// NO work-stealing (R17: ~12.5k same-address atomics cost +124us - dead),
// no fences, static grid-stride (tail ~+6%: the 424 5-tile waves finish on
// an emptying GPU). Spill gates: VGPR 50-64 (not 40), WRITE ~12.5MB.
// Ledger: R11 MFMA-count X, R11 prefetch X, R12 LDS-BW X, R12 ILP X,
// R13 precompute-gather X, R14/R15 fat-body@85regs X(spill), R16 128-edge
// X(spill), R17 stealing X(atomic serialization).

typedef _Float16 f16x8 __attribute__((ext_vector_type(8)));
typedef _Float16 f16x4 __attribute__((ext_vector_type(4)));
typedef float    f32x4 __attribute__((ext_vector_type(4)));

constexpr int NX     = 20000;
constexpr int NROWS  = 50000 * 8;    // NY * K
constexpr int NTILES = NROWS / 16;   // 25000
constexpr int NFRAG  = 48;           // W0a 12 | Wsa 12 | W1a 8 | W0b 8 | W1b 8
constexpr int BW     = 8;            // waves per block
constexpr int BLOCK  = 64 * BW;      // 512
constexpr int GRID   = 768;          // 3 blocks/CU target

__global__ void prep_x(const float* __restrict__ x, _Float16* __restrict__ x16) {
    const int i = blockIdx.x * blockDim.x + threadIdx.x;   // one float4 each
    if (i < NX * 16) {
        float4 v = ((const float4*)x)[i];
        f16x4 o = {(_Float16)v.x, (_Float16)v.y, (_Float16)v.z, (_Float16)v.w};
        *(f16x4*)(x16 + (size_t)i * 4) = o;
    }
}

// relu + repack accumulator (C-layout) into the two K=64 B-fragments.
// frag s element j  <->  acc[t=2s+(j>>2)][r=j&3]   (matches PHI weight layout)
static __device__ __forceinline__ void pack_relu(const f32x4* A, f16x8* bf) {
#pragma unroll
    for (int s = 0; s < 2; ++s) {
        f16x8 r;
#pragma unroll
        for (int e = 0; e < 8; ++e) {
            float v = A[2 * s + (e >> 2)][e & 3];
            r[e] = (_Float16)(v > 0.0f ? v : 0.0f);
        }
        bf[s] = r;
    }
}

__global__ __launch_bounds__(BLOCK, 6)
void pointnet_fused(const _Float16* __restrict__ x16,
                    const float* __restrict__ pos_x,
                    const float* __restrict__ pos_y,
                    const int*   __restrict__ x_idx,
                    const float* __restrict__ W0a, const float* __restrict__ b0a,
                    const float* __restrict__ W1a, const float* __restrict__ b1a,
                    const float* __restrict__ Wsa,
                    const float* __restrict__ W0b, const float* __restrict__ b0b,
                    const float* __restrict__ W1b, const float* __restrict__ b1b,
                    float* __restrict__ out)
{
    __shared__ __align__(16) _Float16 bfrag[NFRAG * 64 * 8];   // 48 KiB
    __shared__ __align__(16) float    bias3f[64];              // b0b (mm4 acc init)
    __shared__ __align__(16) float    bias5f[64];              // b1b (post-max add)

    const int tid = threadIdx.x;

    // ---- fill weight fragments (A operands, transposed; PHI-permuted K) ----
    // grp0 W0a(identity,+b0a@k67)  grp1 Wsa(identity,+b1a@k67)
    // grp2 W1a(PHI) grp3 W0b(PHI) grp4 W1b(PHI)
    for (int p = tid; p < NFRAG * 64; p += BLOCK) {
        const int f = p >> 6, l = p & 63;
        const int q = l >> 4, n0 = l & 15;
        int grp, fl;
        if      (f < 12) { grp = 0; fl = f; }
        else if (f < 24) { grp = 1; fl = f - 12; }
        else if (f < 32) { grp = 2; fl = f - 24; }
        else if (f < 40) { grp = 3; fl = f - 32; }
        else             { grp = 4; fl = f - 40; }
        const int s = fl >> 2, t = fl & 3;
        const int col = t * 16 + n0;
        f16x8 v;
#pragma unroll
        for (int j = 0; j < 8; ++j) {
            const int k = 32 * s + 8 * q + j;
            float val = 0.0f;
            if      (grp == 0) val = (k < 67) ? W0a[k * 64 + col] : (k == 67 ? b0a[col] : 0.0f);
            else if (grp == 1) val = (k < 67) ? Wsa[k * 64 + col] : (k == 67 ? b1a[col] : 0.0f);
            else {
                const float* W = (grp == 2) ? W1a : (grp == 3) ? W0b : W1b;
                const int row = 32 * s + 16 * (j >> 2) + 4 * q + (j & 3);  // PHI(k), s<2
                val = W[row * 64 + col];
            }
            v[j] = (_Float16)val;
        }
        *(f16x8*)&bfrag[p * 8] = v;
    }
    if (tid < 64)       bias3f[tid]      = b0b[tid];
    else if (tid < 128) bias5f[tid - 64] = b1b[tid - 64];
    __syncthreads();

    const int lane = tid & 63;
    const int wv   = tid >> 6;
    const int n0   = lane & 15;   // B col = data row (dr) / C-layout col
    const int q    = lane >> 4;

    const int gwave  = blockIdx.x * BW + wv;
    const int nwaves = GRID * BW;   // 6144

#define WFRAG(fid) (*(const f16x8*)&bfrag[(((fid) * 64) + lane) * 8])

    for (int tile = gwave; tile < NTILES; tile += nwaves) {
        // ---- gather h: lane(n0,q) = h[dr=n0][feats 32s+8q+j] ----
        f16x8 h0, h1, h2;
        {
            const int row = tile * 16 + n0;
            const int xi  = x_idx[row];
            const _Float16* xp = x16 + (long)xi * 64 + q * 8;
            h0 = *(const f16x8*)(xp);
            h1 = *(const f16x8*)(xp + 32);
            f16x8 z = {};
            h2 = z;
            if (q == 0) {                      // k=64..66 diff, k=67 = 1.0 (bias hook)
                const int yi = row >> 3;
#pragma unroll
                for (int j = 0; j < 3; ++j)
                    h2[j] = (_Float16)(pos_x[xi * 3 + j] - pos_y[yi * 3 + j]);
                h2[3] = (_Float16)1.0f;
            }
        }

        // ---- mm3 on raw h: A2 = (h @ Wsa)^T + b1a (k67 hook) ----
        f32x4 A2[4];
#pragma unroll
        for (int t = 0; t < 4; ++t) A2[t] = (f32x4){0.f, 0.f, 0.f, 0.f};
#pragma unroll
        for (int t = 0; t < 4; ++t) A2[t] = __builtin_amdgcn_mfma_f32_16x16x32_f16(WFRAG(12 + t), h0, A2[t], 0, 0, 0);
#pragma unroll
        for (int t = 0; t < 4; ++t) A2[t] = __builtin_amdgcn_mfma_f32_16x16x32_f16(WFRAG(16 + t), h1, A2[t], 0, 0, 0);
#pragma unroll
        for (int t = 0; t < 4; ++t) A2[t] = __builtin_amdgcn_mfma_f32_16x16x32_f16(WFRAG(20 + t), h2, A2[t], 0, 0, 0);

        // ---- relu h in place (pad 1.0 survives) ----
#pragma unroll
        for (int j = 0; j < 8; ++j) {
            h0[j] = h0[j] > (_Float16)0 ? h0[j] : (_Float16)0;
            h1[j] = h1[j] > (_Float16)0 ? h1[j] : (_Float16)0;
            h2[j] = h2[j] > (_Float16)0 ? h2[j] : (_Float16)0;
        }

        // ---- mm1: A1 = (relu(h) @ W0a)^T + b0a (k67 hook) ----
        f32x4 A1[4];
#pragma unroll
        for (int t = 0; t < 4; ++t) A1[t] = (f32x4){0.f, 0.f, 0.f, 0.f};
#pragma unroll
        for (int t = 0; t < 4; ++t) A1[t] = __builtin_amdgcn_mfma_f32_16x16x32_f16(WFRAG(0 + t), h0, A1[t], 0, 0, 0);
#pragma unroll
        for (int t = 0; t < 4; ++t) A1[t] = __builtin_amdgcn_mfma_f32_16x16x32_f16(WFRAG(4 + t), h1, A1[t], 0, 0, 0);
#pragma unroll
        for (int t = 0; t < 4; ++t) A1[t] = __builtin_amdgcn_mfma_f32_16x16x32_f16(WFRAG(8 + t), h2, A1[t], 0, 0, 0);

        // ---- mm2: A2 += (relu(net) @ W1a)^T ----
        f16x8 bf[2];
        pack_relu(A1, bf);
#pragma unroll
        for (int s = 0; s < 2; ++s)
#pragma unroll
            for (int t = 0; t < 4; ++t)
                A2[t] = __builtin_amdgcn_mfma_f32_16x16x32_f16(WFRAG(24 + s * 4 + t), bf[s], A2[t], 0, 0, 0);

        // ---- mm4: A1 := b0b (broadcast LDS init) + (relu(h2) @ W0b)^T ----
        //      (A1 slots reused -> only 2 acc arrays ever live)
        pack_relu(A2, bf);
#pragma unroll
        for (int t = 0; t < 4; ++t) A1[t] = *(const f32x4*)&bias3f[16 * t + 4 * q];
#pragma unroll
        for (int s = 0; s < 2; ++s)
#pragma unroll
            for (int t = 0; t < 4; ++t)
                A1[t] = __builtin_amdgcn_mfma_f32_16x16x32_f16(WFRAG(32 + s * 4 + t), bf[s], A1[t], 0, 0, 0);

        // ---- mm5: A2 += (relu(net2) @ W1b)^T  -> h3^T (b1b deferred past max) ----
        pack_relu(A1, bf);
#pragma unroll
        for (int s = 0; s < 2; ++s)
#pragma unroll
            for (int t = 0; t < 4; ++t)
                A2[t] = __builtin_amdgcn_mfma_f32_16x16x32_f16(WFRAG(40 + s * 4 + t), bf[s], A2[t], 0, 0, 0);

        // ---- epilogue: in-register f16 max over dr (lane bits 0..2), no LDS ----
        {
            union U { f16x8 h; int i[4]; };
            U pa, pb;
#pragma unroll
            for (int e = 0; e < 8; ++e) {
                pa.h[e] = (_Float16)A2[(e >> 2)][e & 3];       // feats t=0,1
                pb.h[e] = (_Float16)A2[2 + (e >> 2)][e & 3];   // feats t=2,3
            }
#pragma unroll
            for (int st = 0; st < 3; ++st) {
                const int m = 1 << st;                         // xor 1,2,4
                U qa, qb;
#pragma unroll
                for (int d = 0; d < 4; ++d) {
                    qa.i[d] = __shfl_xor(pa.i[d], m, 64);
                    qb.i[d] = __shfl_xor(pb.i[d], m, 64);
                }
#pragma unroll
                for (int e = 0; e < 8; ++e) {
                    pa.h[e] = pa.h[e] > qa.h[e] ? pa.h[e] : qa.h[e];
                    pb.h[e] = pb.h[e] > qb.h[e] ? pb.h[e] : qb.h[e];
                }
            }
            if ((n0 & 7) == 0) {
                const int y = tile * 2 + (n0 >> 3);
                float* op = out + (long)y * 64;
#pragma unroll
                for (int t = 0; t < 4; ++t) {
                    const f32x4 bb = *(const f32x4*)&bias5f[16 * t + 4 * q];
                    const int e0 = (t & 1) * 4;
                    float4 vst;
                    if (t < 2) vst = {(float)pa.h[e0 + 0] + bb[0], (float)pa.h[e0 + 1] + bb[1],
                                      (float)pa.h[e0 + 2] + bb[2], (float)pa.h[e0 + 3] + bb[3]};
                    else       vst = {(float)pb.h[e0 + 0] + bb[0], (float)pb.h[e0 + 1] + bb[1],
                                      (float)pb.h[e0 + 2] + bb[2], (float)pb.h[e0 + 3] + bb[3]};
                    *(float4*)(op + 16 * t + 4 * q) = vst;
                }
            }
        }
    }
#undef WFRAG
}

extern "C" void kernel_launch(void* const* d_in, const int* in_sizes, int n_in,
                              void* d_out, int out_size, void* d_ws, size_t ws_size,
                              hipStream_t stream) {
    (void)in_sizes; (void)n_in; (void)ws_size; (void)out_size;
    _Float16* x16 = (_Float16*)d_ws;

    prep_x<<<(NX * 16 + 255) / 256, 256, 0, stream>>>((const float*)d_in[0], x16);

    pointnet_fused<<<GRID, BLOCK, 0, stream>>>(
        x16,
        (const float*)d_in[1],   // pos_x
        (const float*)d_in[2],   // pos_y
        (const int*)  d_in[3],   // x_idx
        (const float*)d_in[5],  (const float*)d_in[6],   // W0a, b0a
        (const float*)d_in[7],  (const float*)d_in[8],   // W1a, b1a
        (const float*)d_in[9],                            // Wsa
        (const float*)d_in[10], (const float*)d_in[11],  // W0b, b0b
        (const float*)d_in[12], (const float*)d_in[13],  // W1b, b1b
        (float*)d_out);
}